// Round 10
// baseline (249.854 us; speedup 1.0000x reference)
//
#include <hip/hip_runtime.h>
#include <cstdint>

// B=4096, T=512, I=3, H=32, C=3
#define B_TOT 4096
#define T_LEN 512
#define CHUNK 128
#define LOG2E 1.44269504088896340736f
#define HSTR  40   // hbuf inner stride in halves (80 B): 16B-aligned b128 frags

typedef _Float16 f16x8 __attribute__((ext_vector_type(8)));
typedef _Float16 f16x4 __attribute__((ext_vector_type(4)));
typedef float    f32x4 __attribute__((ext_vector_type(4)));

__device__ __forceinline__ float ex2(float v)  { return __builtin_amdgcn_exp2f(v); }
__device__ __forceinline__ float rcp_(float v) { return __builtin_amdgcn_rcpf(v); }

// R10: dual-tile interleave. Block = 4 waves handles TWO independent 8-batch
// tiles (A = batches [16b,16b+8), B = +8) in lock-step: per iteration one step
// of A and one of B, ONE barrier per two steps. The two recurrence chains are
// data-independent -> intra-wave ILP hides each chain's ds_read/trans latency
// with the sibling tile's issue. 256 blocks = 1 block/CU, 1 wave/SIMD.
// Per-tile structure is R5/R8 (best measured): wave w owns hids [8w,8w+8) via
// two gate-MFMAs sharing one B fragment (cols = batch n&7, dup x2):
//   MFMA#1 rows m: gate=m&3, hid=8w+(m>>2); MFMA#2: hid=8w+4+(m>>2)
// Lane (n,kq) state: (batch n&7, hid 8w+kq+(n>=8?4:0)); 1-of-2 select.
// exp2 scales folded into A rows; bias via x-MFMA K-slot 3 (pad staged = 1.0).
// Merged-reciprocal gate math: 5 exp2 + 2 rcp per state per step.
__global__ __launch_bounds__(256, 1)
void lstm_dt(const float* __restrict__ x,
             const float* __restrict__ W_ih,
             const float* __restrict__ W_hh,
             const float* __restrict__ b_ih,
             const float* __restrict__ b_hh,
             const float* __restrict__ W_fc,
             const float* __restrict__ b_fc,
             float* __restrict__ out)
{
    __shared__ __align__(16) _Float16 hbuf[2][16][HSTR];   // 2.5 KB (A: rows 0-7, B: 8-15)
    __shared__ __align__(16) _Float16 xbuf[CHUNK][16][4];  // 16 KB

    const int tid  = threadIdx.x;
    const int wave = tid >> 6;        // 0..3
    const int lane = tid & 63;
    const int n    = lane & 15;
    const int kq   = lane >> 4;
    const int nb   = n & 7;           // batch column within a tile
    const int tb   = blockIdx.x * 16;

    // ---- A-fragment rows (m = n) for the two gate-MFMAs (shared by tiles) ----
    const int   gate_m = n & 3;
    const int   hl_m   = n >> 2;                       // 0..3
    const int   R1     = gate_m * 32 + 8 * wave + hl_m;
    const int   R2     = R1 + 4;
    const float sm     = (gate_m == 2) ? (-2.0f * LOG2E) : (-LOG2E);

    f16x8 aW1, aW2;
#pragma unroll
    for (int j = 0; j < 8; ++j) {
        aW1[j] = (_Float16)(sm * W_hh[R1 * 32 + 8 * kq + j]);
        aW2[j] = (_Float16)(sm * W_hh[R2 * 32 + 8 * kq + j]);
    }
    f16x8 a21 = {}, a22 = {};         // x-weights + bias (kq==0 lanes carry K 0..3)
    if (kq == 0) {
        a21[0] = (_Float16)(sm * W_ih[R1 * 3 + 0]);
        a21[1] = (_Float16)(sm * W_ih[R1 * 3 + 1]);
        a21[2] = (_Float16)(sm * W_ih[R1 * 3 + 2]);
        a21[3] = (_Float16)(sm * (b_ih[R1] + b_hh[R1]));
        a22[0] = (_Float16)(sm * W_ih[R2 * 3 + 0]);
        a22[1] = (_Float16)(sm * W_ih[R2 * 3 + 1]);
        a22[2] = (_Float16)(sm * W_ih[R2 * 3 + 2]);
        a22[3] = (_Float16)(sm * (b_ih[R2] + b_hh[R2]));
    }

    // my state: (batch nb, hid_s) in each tile
    const int hid_s = 8 * wave + kq + ((n >> 3) ? 4 : 0);

    // zero h(0) buffer (hbuf[0] = 16*HSTR halves = 320 ints)
    for (int i = tid; i < 320; i += 256) ((int*)&hbuf[0][0][0])[i] = 0;

    const float K2 = -2.0f * LOG2E;
    float cA = 0.0f, cB = 0.0f;
    const f32x4 z = {0.f, 0.f, 0.f, 0.f};
    f32x4 ax1A, ax2A, ax1B, ax2B;     // prefetched x-contributions (incl. bias)

    const bool hi = (n >> 3) != 0;

    for (int tc = 0; tc < T_LEN; tc += CHUNK) {
        // ---- stage x chunk (both tiles) as fp16, pad slot = 1.0 (bias trick) ----
#pragma unroll
        for (int s = 0; s < 8; ++s) {
            const int idx = tid + s * 256;          // 2048 (t,m) pairs
            const int tl = idx >> 4, m = idx & 15;
            const float* xp = x + ((size_t)(tb + m) * T_LEN + (tc + tl)) * 3;
            f16x4 v;
            v[0] = (_Float16)xp[0]; v[1] = (_Float16)xp[1];
            v[2] = (_Float16)xp[2]; v[3] = (_Float16)1.0f;
            *(f16x4*)&xbuf[tl][m][0] = v;
        }
        __syncthreads();

        {   // accx for first step of chunk, both tiles
            const f16x4 xa = *(const f16x4*)&xbuf[0][nb][0];
            const f16x4 xb = *(const f16x4*)&xbuf[0][nb + 8][0];
            const f16x8 bA = __builtin_shufflevector(xa, xa, 0, 1, 2, 3, 0, 1, 2, 3);
            const f16x8 bB = __builtin_shufflevector(xb, xb, 0, 1, 2, 3, 0, 1, 2, 3);
            ax1A = __builtin_amdgcn_mfma_f32_16x16x32_f16(a21, bA, z, 0, 0, 0);
            ax2A = __builtin_amdgcn_mfma_f32_16x16x32_f16(a22, bA, z, 0, 0, 0);
            ax1B = __builtin_amdgcn_mfma_f32_16x16x32_f16(a21, bB, z, 0, 0, 0);
            ax2B = __builtin_amdgcn_mfma_f32_16x16x32_f16(a22, bB, z, 0, 0, 0);
        }

#pragma unroll 2
        for (int tt = 0; tt < CHUNK; ++tt) {
            const int p = tt & 1;

            // issue both tiles' h-reads back-to-back (independent)
            const f16x8 bhA = *(const f16x8*)&hbuf[p][nb][8 * kq];
            const f16x8 bhB = *(const f16x8*)&hbuf[p][nb + 8][8 * kq];

            const f32x4 acA1 = __builtin_amdgcn_mfma_f32_16x16x32_f16(aW1, bhA, ax1A, 0, 0, 0);
            const f32x4 acA2 = __builtin_amdgcn_mfma_f32_16x16x32_f16(aW2, bhA, ax2A, 0, 0, 0);
            const f32x4 acB1 = __builtin_amdgcn_mfma_f32_16x16x32_f16(aW1, bhB, ax1B, 0, 0, 0);
            const f32x4 acB2 = __builtin_amdgcn_mfma_f32_16x16x32_f16(aW2, bhB, ax2B, 0, 0, 0);

            // ---- tile A gate math (merged-reciprocal: 5 exp2 + 2 rcp) ----
            {
                const float a0 = hi ? acA2[0] : acA1[0];
                const float a1 = hi ? acA2[1] : acA1[1];
                const float a2 = hi ? acA2[2] : acA1[2];
                const float a3 = hi ? acA2[3] : acA1[3];
                const float ei = ex2(a0), ef = ex2(a1), eg = ex2(a2), eo = ex2(a3);
                const float pi = 1.0f + ei, pf = 1.0f + ef, pg = 1.0f + eg;
                const float mg = 1.0f - eg;
                const float pp = pi * pg, qn = mg * pf;
                const float num = fmaf(cA, pp, qn);
                cA = num * rcp_(pf * pp);
                const float ec = ex2(cA * K2);
                const float po = 1.0f + eo, pc = 1.0f + ec, mc = 1.0f - ec;
                const float h = mc * rcp_(po * pc);
                hbuf[p ^ 1][nb][hid_s] = (_Float16)h;
            }
            // ---- tile B gate math (independent chain -> interleaves with A) ----
            {
                const float a0 = hi ? acB2[0] : acB1[0];
                const float a1 = hi ? acB2[1] : acB1[1];
                const float a2 = hi ? acB2[2] : acB1[2];
                const float a3 = hi ? acB2[3] : acB1[3];
                const float ei = ex2(a0), ef = ex2(a1), eg = ex2(a2), eo = ex2(a3);
                const float pi = 1.0f + ei, pf = 1.0f + ef, pg = 1.0f + eg;
                const float mg = 1.0f - eg;
                const float pp = pi * pg, qn = mg * pf;
                const float num = fmaf(cB, pp, qn);
                cB = num * rcp_(pf * pp);
                const float ec = ex2(cB * K2);
                const float po = 1.0f + eo, pc = 1.0f + ec, mc = 1.0f - ec;
                const float h = mc * rcp_(po * pc);
                hbuf[p ^ 1][nb + 8][hid_s] = (_Float16)h;
            }

            // prefetch next step's x-parts (independent of h) before the barrier
            const int ttn = (tt + 1) & (CHUNK - 1);
            const f16x4 xa = *(const f16x4*)&xbuf[ttn][nb][0];
            const f16x4 xb = *(const f16x4*)&xbuf[ttn][nb + 8][0];
            const f16x8 bA = __builtin_shufflevector(xa, xa, 0, 1, 2, 3, 0, 1, 2, 3);
            const f16x8 bB = __builtin_shufflevector(xb, xb, 0, 1, 2, 3, 0, 1, 2, 3);
            ax1A = __builtin_amdgcn_mfma_f32_16x16x32_f16(a21, bA, z, 0, 0, 0);
            ax2A = __builtin_amdgcn_mfma_f32_16x16x32_f16(a22, bA, z, 0, 0, 0);
            ax1B = __builtin_amdgcn_mfma_f32_16x16x32_f16(a21, bB, z, 0, 0, 0);
            ax2B = __builtin_amdgcn_mfma_f32_16x16x32_f16(a22, bB, z, 0, 0, 0);

            __syncthreads();   // one barrier per TWO logical LSTM steps
        }
    }

    // ---- epilogue: out[tb+m][cc] = b_fc[cc] + sum_k W_fc[cc][k]*h[m][k] ----
    // final h (t=512) is in hbuf[0]; last loop barrier ordered it.
    if (tid < 48) {
        const int m = tid / 3, cc = tid % 3;
        float acc = b_fc[cc];
#pragma unroll
        for (int k = 0; k < 32; ++k)
            acc = fmaf(W_fc[cc * 32 + k], (float)hbuf[0][m][k], acc);
        out[(tb + m) * 3 + cc] = acc;
    }
}

extern "C" void kernel_launch(void* const* d_in, const int* in_sizes, int n_in,
                              void* d_out, int out_size, void* d_ws, size_t ws_size,
                              hipStream_t stream) {
    const float* x    = (const float*)d_in[0];
    const float* W_ih = (const float*)d_in[1];
    const float* W_hh = (const float*)d_in[2];
    const float* b_ih = (const float*)d_in[3];
    const float* b_hh = (const float*)d_in[4];
    const float* W_fc = (const float*)d_in[5];
    const float* b_fc = (const float*)d_in[6];
    float* out = (float*)d_out;

    dim3 grid(B_TOT / 16);   // 256 blocks = 1 per CU; two tiles per block
    dim3 block(256);         // 4 waves
    lstm_dt<<<grid, block, 0, stream>>>(x, W_ih, W_hh, b_ih, b_hh, W_fc, b_fc, out);
}

// Round 11
// 190.823 us; speedup vs baseline: 1.3093x; 1.3093x over previous
//
#include <hip/hip_runtime.h>
#include <cstdint>

// B=4096, T=512, I=3, H=32, C=3
#define B_TOT 4096
#define T_LEN 512
#define CHUNK 128
#define LOG2E 1.44269504088896340736f
#define HSTR  40   // hbuf inner stride in halves (80 B): 16B-aligned b128 frags

typedef _Float16 f16x8 __attribute__((ext_vector_type(8)));
typedef _Float16 f16x4 __attribute__((ext_vector_type(4)));
typedef float    f32x4 __attribute__((ext_vector_type(4)));

__device__ __forceinline__ float ex2(float v)  { return __builtin_amdgcn_exp2f(v); }
__device__ __forceinline__ float rcp_(float v) { return __builtin_amdgcn_rcpf(v); }

// R8 structure (measured best): 8-batch tile, 4 waves/block, 512 blocks ->
// 2 independent barrier domains per CU. Wave w owns hids [8w,8w+8) via TWO
// gate-MFMAs sharing one B fragment (cols = batch n&7, dup x2):
//   MFMA#1 rows m: gate=m&3, hid=8w+(m>>2); MFMA#2: hid=8w+4+(m>>2)
// Lane (n,kq) state: (batch n&7, hid 8w+kq+(n>=8?4:0)); 1-of-2 select.
// exp2 scales folded into A rows; bias via x-MFMA K-slot 3 (pad staged = 1.0).
// Merged-reciprocal gate math: 5 exp2 + 2 rcp per state per step.
//
// R11 delta: x-pipeline off the critical path. The xv ds_read_b64 for step
// tt+1 is issued at the TOP of iteration tt, alongside the bh ds_read_b128 —
// their ~120-cyc latencies overlap. The accx MFMAs (consuming xv, producing
// next step's C operand) run after the h-write on already-arrived data: pure
// issue, no lgkm wait in the pre-barrier tail. This removes ~150 cyc/step of
// serial chain that R8 spent waiting on the xv read before its barrier.
__global__ __launch_bounds__(256, 2)
void lstm_xp(const float* __restrict__ x,
             const float* __restrict__ W_ih,
             const float* __restrict__ W_hh,
             const float* __restrict__ b_ih,
             const float* __restrict__ b_hh,
             const float* __restrict__ W_fc,
             const float* __restrict__ b_fc,
             float* __restrict__ out)
{
    __shared__ __align__(16) _Float16 hbuf[2][8][HSTR];   // 1.25 KB
    __shared__ __align__(16) _Float16 xbuf[CHUNK][8][4];  // 8 KB

    const int tid  = threadIdx.x;
    const int wave = tid >> 6;        // 0..3
    const int lane = tid & 63;
    const int n    = lane & 15;
    const int kq   = lane >> 4;
    const int nb   = n & 7;           // batch column
    const int tb   = blockIdx.x * 8;

    // ---- A-fragment rows (m = n) for the two gate-MFMAs ----
    const int   gate_m = n & 3;
    const int   hl_m   = n >> 2;                       // 0..3
    const int   R1     = gate_m * 32 + 8 * wave + hl_m;
    const int   R2     = R1 + 4;
    const float sm     = (gate_m == 2) ? (-2.0f * LOG2E) : (-LOG2E);

    f16x8 aW1, aW2;
#pragma unroll
    for (int j = 0; j < 8; ++j) {
        aW1[j] = (_Float16)(sm * W_hh[R1 * 32 + 8 * kq + j]);
        aW2[j] = (_Float16)(sm * W_hh[R2 * 32 + 8 * kq + j]);
    }
    f16x8 a21 = {}, a22 = {};         // x-weights + bias (kq==0 lanes carry K 0..3)
    if (kq == 0) {
        a21[0] = (_Float16)(sm * W_ih[R1 * 3 + 0]);
        a21[1] = (_Float16)(sm * W_ih[R1 * 3 + 1]);
        a21[2] = (_Float16)(sm * W_ih[R1 * 3 + 2]);
        a21[3] = (_Float16)(sm * (b_ih[R1] + b_hh[R1]));
        a22[0] = (_Float16)(sm * W_ih[R2 * 3 + 0]);
        a22[1] = (_Float16)(sm * W_ih[R2 * 3 + 1]);
        a22[2] = (_Float16)(sm * W_ih[R2 * 3 + 2]);
        a22[3] = (_Float16)(sm * (b_ih[R2] + b_hh[R2]));
    }

    // my state: (batch nb, hid_s)
    const int hid_s = 8 * wave + kq + ((n >> 3) ? 4 : 0);

    // zero h(0) buffer (hbuf[0] = 8*HSTR halves = 160 ints)
    if (tid < 160) ((int*)&hbuf[0][0][0])[tid] = 0;

    const float K2 = -2.0f * LOG2E;
    float c = 0.0f;
    const f32x4 z = {0.f, 0.f, 0.f, 0.f};
    f32x4 accx1, accx2;   // x-contribution (incl. bias) for the CURRENT step

    const bool hi = (n >> 3) != 0;

    for (int tc = 0; tc < T_LEN; tc += CHUNK) {
        // ---- stage x chunk as fp16, pad slot = 1.0 (bias trick) ----
#pragma unroll
        for (int s = 0; s < 4; ++s) {
            const int idx = tid + s * 256;          // 1024 (t,m) pairs
            const int tl = idx >> 3, m = idx & 7;
            const float* xp = x + ((size_t)(tb + m) * T_LEN + (tc + tl)) * 3;
            f16x4 v;
            v[0] = (_Float16)xp[0]; v[1] = (_Float16)xp[1];
            v[2] = (_Float16)xp[2]; v[3] = (_Float16)1.0f;
            *(f16x4*)&xbuf[tl][m][0] = v;
        }
        __syncthreads();

        {   // accx for first step of chunk (b2 rows k>=4 are don't-cares)
            const f16x4 xv = *(const f16x4*)&xbuf[0][nb][0];
            const f16x8 b2 = __builtin_shufflevector(xv, xv, 0, 1, 2, 3, 0, 1, 2, 3);
            accx1 = __builtin_amdgcn_mfma_f32_16x16x32_f16(a21, b2, z, 0, 0, 0);
            accx2 = __builtin_amdgcn_mfma_f32_16x16x32_f16(a22, b2, z, 0, 0, 0);
        }

#pragma unroll 2
        for (int tt = 0; tt < CHUNK; ++tt) {
            const int p = tt & 1;   // tc is a multiple of CHUNK (even)

            // --- issue both LDS reads back-to-back; latencies overlap ---
            const f16x8 bh  = *(const f16x8*)&hbuf[p][nb][8 * kq];         // h(t)
            const int ttn = (tt + 1) & (CHUNK - 1);   // wrap -> dummy, recomputed
            const f16x4 xvN = *(const f16x4*)&xbuf[ttn][nb][0];            // x(t+1)

            const f32x4 ac1 = __builtin_amdgcn_mfma_f32_16x16x32_f16(aW1, bh, accx1, 0, 0, 0);
            const f32x4 ac2 = __builtin_amdgcn_mfma_f32_16x16x32_f16(aW2, bh, accx2, 0, 0, 0);

            const float a0 = hi ? ac2[0] : ac1[0];   // i' (scaled pre-act)
            const float a1 = hi ? ac2[1] : ac1[1];   // f'
            const float a2 = hi ? ac2[2] : ac1[2];   // g' (2x scale)
            const float a3 = hi ? ac2[3] : ac1[3];   // o'

            // merged-reciprocal gate math: 5 exp2 + 2 rcp per state
            const float ei = ex2(a0), ef = ex2(a1), eg = ex2(a2), eo = ex2(a3);
            const float pi = 1.0f + ei, pf = 1.0f + ef, pg = 1.0f + eg;
            const float mg = 1.0f - eg;
            const float pp  = pi * pg;
            const float qn  = mg * pf;
            const float num = fmaf(c, pp, qn);
            c = num * rcp_(pf * pp);

            const float ec = ex2(c * K2);
            const float po = 1.0f + eo, pc = 1.0f + ec, mc = 1.0f - ec;
            const float h  = mc * rcp_(po * pc);

            hbuf[p ^ 1][nb][hid_s] = (_Float16)h;

            // --- next step's accx: xvN arrived during the trans chain ->
            //     pure MFMA issue here, no lgkm wait in the pre-barrier tail ---
            const f16x8 b2 = __builtin_shufflevector(xvN, xvN, 0, 1, 2, 3, 0, 1, 2, 3);
            accx1 = __builtin_amdgcn_mfma_f32_16x16x32_f16(a21, b2, z, 0, 0, 0);
            accx2 = __builtin_amdgcn_mfma_f32_16x16x32_f16(a22, b2, z, 0, 0, 0);

            __syncthreads();
        }
    }

    // ---- epilogue: out[tb+m][cc] = b_fc[cc] + sum_k W_fc[cc][k]*h[m][k] ----
    // final h (t=512) is in hbuf[0]; last loop barrier ordered it.
    if (tid < 24) {
        const int m = tid / 3, cc = tid % 3;
        float acc = b_fc[cc];
#pragma unroll
        for (int k = 0; k < 32; ++k)
            acc = fmaf(W_fc[cc * 32 + k], (float)hbuf[0][m][k], acc);
        out[(tb + m) * 3 + cc] = acc;
    }
}

extern "C" void kernel_launch(void* const* d_in, const int* in_sizes, int n_in,
                              void* d_out, int out_size, void* d_ws, size_t ws_size,
                              hipStream_t stream) {
    const float* x    = (const float*)d_in[0];
    const float* W_ih = (const float*)d_in[1];
    const float* W_hh = (const float*)d_in[2];
    const float* b_ih = (const float*)d_in[3];
    const float* b_hh = (const float*)d_in[4];
    const float* W_fc = (const float*)d_in[5];
    const float* b_fc = (const float*)d_in[6];
    float* out = (float*)d_out;

    dim3 grid(B_TOT / 8);    // 512 blocks -> 2 independent barrier domains per CU
    dim3 block(256);         // 4 waves, 8 hids/wave
    lstm_xp<<<grid, block, 0, stream>>>(x, W_ih, W_hh, b_ih, b_hh, W_fc, b_fc, out);
}